// Round 6
// baseline (141.168 us; speedup 1.0000x reference)
//
#include <hip/hip_runtime.h>

#define IMG_H 480
#define IMG_W 640
#define OUT_H 470    // 480 - 10
#define OUT_W 630    // 640 - 10
#define NBATCH 32
#define SW 126       // output columns per wave (63 lanes x 2); 5*126 = 630 exact
#define NSTRIPE 5
#define RCH 34       // output rows per wave-chunk (14*34 = 476 >= 470, tail masked)
#define NCHUNK 14
#define WPB 2        // waves per block (independent row-chunks, no sync)
#define NROWS (RCH + 10)   // 44 input rows = 4*11 -> slot/phase fold to literals

#define ROW_F  192   // floats per staged image-row (3 x 64-lane dword chunks)
#define SLOT_F 384   // floats per slot (2 images x ROW_F)
#define NSLOT  11    // slot index == ring phase literal; overwrite 8 steps after read

#define SSIM_C1 1.0f // (0.01*100)^2
#define SSIM_C2 9.0f // (0.03*100)^2

typedef float v2f __attribute__((ext_vector_type(2)));

// Normalized 11-tap Gaussian (sigma=1.5), matches numpy fp32 window to ~1e-7 rel.
__device__ constexpr float WG[11] = {
    0.00102838f, 0.00759876f, 0.03600077f, 0.10936068f, 0.21300554f,
    0.26601173f,
    0.21300554f, 0.10936068f, 0.03600077f, 0.00759876f, 0.00102838f
};

__device__ __forceinline__ v2f pk_fma(v2f a, v2f b, v2f c) {
    return __builtin_elementwise_fma(a, b, c);
}

// Fire-and-forget global->LDS DMA, 4B per lane, lane-contiguous LDS dest.
#define GLL(gsrc, ldst)                                                       \
  __builtin_amdgcn_global_load_lds(                                           \
      (const __attribute__((address_space(1))) void*)(gsrc),                  \
      (__attribute__((address_space(3))) void*)(ldst), 4, 0, 0)

// HISTORY: R1-R5 all pinned at ~57-59us, VALUBusy 42-44%, for every tiling /
// wave-packing / prefetch-depth / code-footprint variant. Model: per wave-step
// ~560 cyc VALU issue vs ~1500 cyc measured -> ~900 cyc uncovered memory
// latency per step. VGPR-destination loads can't be hoisted far enough
// (register pressure pins the scoreboard wait right before use). R6: stage
// rows via global_load_lds into a per-wave LDS ring (no VGPR destinations),
// prefetch distance 3 rows (~1800 cyc slack), retire with counted
// s_waitcnt vmcnt(18) -- only row IT's 6 loads must be complete. ds_read_b64
// latency ~120 cyc is covered by the h-pass.
// vmcnt BOOKKEEPING: exactly 6 global_load_lds per step, 18 in prologue.
// At each step: outstanding = 24 after issue; vmcnt(18) retires oldest 6
// (vmcnt retires in issue order). NO other VMEM ops inside the loop.
// *** INDEXING MUST BE COMPILE-TIME *** PP is a post-unroll literal (44-step
// straight-line body; 44 = 4*11 -> P = slot = PP%11 literal).
// Sentinels: absmax 0 (race), WRITE_SIZE ~70 KB (spill), LDS_Block 33792.
#define STEP(IT, PP)                                                          \
  {                                                                           \
    const int P   = (PP) % 11;              /* ring phase + read slot  */     \
    const int wsl = ((PP) + 3) % 11;        /* write slot for row IT+3 */     \
    /* 1. stage row IT+3 into slot wsl (clamped; tail overshoot ok) */        \
    {                                                                         \
      int gy = y0 + (IT) + 3; if (gy > IMG_H - 1) gy = IMG_H - 1;             \
      const float* r1 = p1 + gy * IMG_W;                                      \
      const float* r2 = p2 + gy * IMG_W;                                      \
      _Pragma("unroll")                                                       \
      for (int i = 0; i < 3; ++i) {                                           \
        GLL(r1 + coff[i], &swave[wsl * SLOT_F +         i * 64]);             \
        GLL(r2 + coff[i], &swave[wsl * SLOT_F + ROW_F + i * 64]);             \
      }                                                                       \
    }                                                                         \
    /* 2. retire row IT's 6 staged loads (24 outstanding -> <=18) */          \
    asm volatile("s_waitcnt vmcnt(18)" ::: "memory");                         \
    /* 3. LDS -> regs: 6 v2f pairs per image (ds_read_b64, 8B aligned) */     \
    v2f pb[2][6];                                                             \
    _Pragma("unroll")                                                         \
    for (int k = 0; k < 6; ++k) {                                             \
      pb[0][k] = *(const v2f*)&swave[P * SLOT_F +         2 * lane + 2 * k];  \
      pb[1][k] = *(const v2f*)&swave[P * SLOT_F + ROW_F + 2 * lane + 2 * k];  \
    }                                                                         \
    /* 4. h-pass on row IT, packed over output cols (A,B) */                  \
    v2f h1  = (v2f){0.f,0.f}, h2  = (v2f){0.f,0.f};                           \
    v2f h11 = (v2f){0.f,0.f}, h22 = (v2f){0.f,0.f}, h12 = (v2f){0.f,0.f};     \
    _Pragma("unroll")                                                         \
    for (int j = 0; j < 11; ++j) {                                            \
      const v2f wj = (v2f){WG[j], WG[j]};                                     \
      v2f q1, q2;                                                             \
      if (j & 1) {                                                            \
        q1 = (v2f){pb[0][j >> 1].y, pb[0][(j >> 1) + 1].x};                   \
        q2 = (v2f){pb[1][j >> 1].y, pb[1][(j >> 1) + 1].x};                   \
      } else {                                                                \
        q1 = pb[0][j >> 1];                                                   \
        q2 = pb[1][j >> 1];                                                   \
      }                                                                       \
      const v2f t1 = wj * q1;                                                 \
      const v2f t2 = wj * q2;                                                 \
      h1 += t1; h2 += t2;                                                     \
      h11 = pk_fma(t1, q1, h11);                                              \
      h22 = pk_fma(t2, q2, h22);                                              \
      h12 = pk_fma(t1, q2, h12);                                              \
    }                                                                         \
    /* 5. vertical ring update: 5 pk_fma per slot */                          \
    _Pragma("unroll")                                                         \
    for (int sl = 0; sl < 11; ++sl) {                                         \
      const float wt = WG[(P - sl + 11) % 11];                                \
      const v2f wv2 = (v2f){wt, wt};                                          \
      acc[sl][0] = pk_fma(wv2, h1,  acc[sl][0]);                              \
      acc[sl][1] = pk_fma(wv2, h2,  acc[sl][1]);                              \
      acc[sl][2] = pk_fma(wv2, h11, acc[sl][2]);                              \
      acc[sl][3] = pk_fma(wv2, h22, acc[sl][3]);                              \
      acc[sl][4] = pk_fma(wv2, h12, acc[sl][4]);                              \
    }                                                                         \
    /* 6. slot sc got its w[10] tap -> output row y = IT-10 completes */      \
    const int sc = (P + 1) % 11;                                              \
    if ((IT) >= 10 && (y0 + (IT) - 10) < OUT_H) {                             \
      const v2f m1 = acc[sc][0], m2 = acc[sc][1];                             \
      const v2f msq1 = m1 * m1, msq2 = m2 * m2, mu12 = m1 * m2;               \
      const v2f two = (v2f){2.f, 2.f};                                        \
      const v2f c1v = (v2f){SSIM_C1, SSIM_C1};                                \
      const v2f c2v = (v2f){SSIM_C2, SSIM_C2};                                \
      const v2f vA = pk_fma(two, acc[sc][4] - mu12, c2v);                     \
      const v2f vB = (acc[sc][2] - msq1) + (acc[sc][3] - msq2) + c2v;         \
      const v2f num = pk_fma(two, mu12, c1v) * vA;                            \
      const v2f den = (msq1 + msq2 + c1v) * vB;                               \
      if (validA) lsum = fmaf(num.x, __builtin_amdgcn_rcpf(den.x), lsum);     \
      if (validB) lsum = fmaf(num.y, __builtin_amdgcn_rcpf(den.y), lsum);     \
    }                                                                         \
    _Pragma("unroll")                                                         \
    for (int ch = 0; ch < 5; ++ch) acc[sc][ch] = (v2f){0.f, 0.f};             \
  }

__global__ __launch_bounds__(64 * WPB, 2) void ssim_main(
    const float* __restrict__ img1,
    const float* __restrict__ img2,
    float* __restrict__ partials)
{
    const int lane   = threadIdx.x & 63;
    const int wv     = threadIdx.x >> 6;          // wave id in block, 0..1
    const int stripe = blockIdx.x;
    const int cy     = blockIdx.y * WPB + wv;     // 0..13
    const int b      = blockIdx.z;
    const int x0 = SW * stripe;
    const int y0 = RCH * cy;

    const float* __restrict__ p1 = img1 + (size_t)b * (IMG_H * IMG_W);
    const float* __restrict__ p2 = img2 + (size_t)b * (IMG_H * IMG_W);

    // Per-wave private LDS ring: no cross-wave sharing, no __syncthreads.
    __shared__ __align__(16) float sbuf[WPB][NSLOT * SLOT_F];  // 33,792 B
    float* swave = &sbuf[wv][0];

    // Per-lane staged-column offsets (global col = x0 + 64*i + lane).
    // i=0: max 567, i=1: max 631 -> never clamp; i=2: clamp to 639.
    // LDS cols >= 136 of the last stripe hold duplicated col-639 data, which
    // only the invalid lane 63 ever reads (masked).
    int coff[3];
    coff[0] = x0 + lane;
    coff[1] = x0 + 64 + lane;
    coff[2] = x0 + 128 + lane; if (coff[2] > IMG_W - 1) coff[2] = IMG_W - 1;

    // lane l produces output cols x0+2l (A) and x0+2l+1 (B); lanes 0..62 valid
    const bool validA = (2 * lane     < SW) && (x0 + 2 * lane     < OUT_W);
    const bool validB = (2 * lane + 1 < SW) && (x0 + 2 * lane + 1 < OUT_W);

    // vertical ring: 5 channels (mu1, mu2, s11, s22, s12), each v2f over (A,B)
    v2f acc[11][5];
#pragma unroll
    for (int i = 0; i < 11; ++i)
#pragma unroll
        for (int ch = 0; ch < 5; ++ch) acc[i][ch] = (v2f){0.f, 0.f};

    float lsum = 0.f;

    // prologue: stage rows y0..y0+2 into slots 0..2 (18 outstanding loads).
    // y0 max = 442 -> y0+2 in bounds, no clamp needed.
#pragma unroll
    for (int r = 0; r < 3; ++r) {
        const float* r1 = p1 + (y0 + r) * IMG_W;
        const float* r2 = p2 + (y0 + r) * IMG_W;
#pragma unroll
        for (int i = 0; i < 3; ++i) {
            GLL(r1 + coff[i], &swave[r * SLOT_F +         i * 64]);
            GLL(r2 + coff[i], &swave[r * SLOT_F + ROW_F + i * 64]);
        }
    }

    // 44 rows, straight-line (R5 showed rolled loop hurts; straight-line is
    // the proven-best shape). All slot/phase indices are literals.
#pragma unroll
    for (int p = 0; p < 44; ++p) STEP(p, p)

    // drain remaining staged loads before workgroup teardown (in-flight
    // LDS-DMA to a freed workgroup's LDS is a documented hazard)
    asm volatile("s_waitcnt vmcnt(0)" ::: "memory");

    // per-wave reduction (shfl is wave-scoped, 64 lanes)
#pragma unroll
    for (int off = 32; off > 0; off >>= 1)
        lsum += __shfl_down(lsum, off);
    if (lane == 0)
        partials[(b * NCHUNK + cy) * NSTRIPE + stripe] = lsum;
}

__global__ __launch_bounds__(256) void ssim_reduce(
    const float* __restrict__ partials, float* __restrict__ out)
{
    const int n = NSTRIPE * NCHUNK * NBATCH;  // 2240
    __shared__ double red[256];
    int tid = threadIdx.x;
    double s = 0.0;
    for (int i = tid; i < n; i += 256) s += (double)partials[i];
    red[tid] = s;
    __syncthreads();
    for (int k = 128; k > 0; k >>= 1) {
        if (tid < k) red[tid] += red[tid + k];
        __syncthreads();
    }
    if (tid == 0) {
        double mean = red[0] / (double)((size_t)NBATCH * OUT_H * OUT_W);
        out[0] = (float)((1.0 - mean) * 0.5);
    }
}

extern "C" void kernel_launch(void* const* d_in, const int* in_sizes, int n_in,
                              void* d_out, int out_size, void* d_ws, size_t ws_size,
                              hipStream_t stream)
{
    const float* img1 = (const float*)d_in[0];
    const float* img2 = (const float*)d_in[1];
    float* out = (float*)d_out;
    float* partials = (float*)d_ws;  // 2240 floats = 9.0 KB

    // 5 x 7 x 32 = 1120 blocks x 2 waves = 2240 waves
    dim3 grid(NSTRIPE, NCHUNK / WPB, NBATCH);
    ssim_main<<<grid, dim3(64 * WPB), 0, stream>>>(img1, img2, partials);
    ssim_reduce<<<1, dim3(256), 0, stream>>>(partials, out);
}

// Round 7
// 136.619 us; speedup vs baseline: 1.0333x; 1.0333x over previous
//
#include <hip/hip_runtime.h>

#define IMG_H 480
#define IMG_W 640
#define OUT_H 470    // 480 - 10
#define OUT_W 630    // 640 - 10
#define NBATCH 32
#define SW 126       // output columns per wave (63 lanes x 2); 5*126 = 630 exact
#define NSTRIPE 5
#define RCH 24       // output rows per wave-chunk (24*20 = 480 >= 470, tail masked)
#define NCHUNK 20
#define NROWS (RCH + 10)   // 34 input rows per chunk
#define TD 6         // touch distance in rows (~6 steps = 9000 cyc of lead)

#define SSIM_C1 1.0f // (0.01*100)^2
#define SSIM_C2 9.0f // (0.03*100)^2

typedef float v2f __attribute__((ext_vector_type(2)));

// Normalized 11-tap Gaussian (sigma=1.5), matches numpy fp32 window to ~1e-7 rel.
__device__ constexpr float WG[11] = {
    0.00102838f, 0.00759876f, 0.03600077f, 0.10936068f, 0.21300554f,
    0.26601173f,
    0.21300554f, 0.10936068f, 0.03600077f, 0.00759876f, 0.00102838f
};

// Packed fp32 fma: llvm.fma.v2f32 -> v_pk_fma_f32
__device__ __forceinline__ v2f pk_fma(v2f a, v2f b, v2f c) {
    return __builtin_elementwise_fma(a, b, c);
}

// HISTORY (R1-R6): every structural variant (wave packing, VGPR prefetch
// depth, code footprint, LDS staging) pinned at ~1500 cyc/step vs ~560 cyc
// issue, VALUBusy ~43%. Gap = one HBM-class latency per step: each step's
// demand loads contain ~9 first-touch-anywhere lines (FETCH == compulsory;
// each (row,stripe) segment is read by exactly ONE wave), and at ~1.2
// waves/SIMD nothing covers the wave-wide scoreboard wait. R4 (VGPR buffers)
// failed: buffer-reg reuse pins the wait at 1 step. R6 (LDS-DMA) failed:
// global_load_lds shares lgkmcnt with ds_read -> per-step full drain (5100
// cyc/step, 133us). R7: TOUCH loads -- results never consumed in the loop,
// so NOTHING waits on them; they warm L1/L2 six rows ahead. Demand loads
// then hit cache (~100-300 cyc), which one step of issue latency covers.
//   - touch dest regs rotate x2: WAW reuse only after 2 steps (~3000 cyc
//     > miss latency) -> no WAW stall. Consumed by asm keep-alive AFTER the
//     loop (rule #17: prevents DCE; single wait at kernel end).
//   - in-order vmcnt: any touch is >=1 step (~1500cyc) older than the
//     demand wait that follows it -> already retired, never inflates waits.
//   - lanes stride 3 cols (< 32-dword line) -> every 128B line of the
//     138-col segment touched; clamped in-bounds, values finite.
// *** INDEXING MUST BE COMPILE-TIME *** PP is a post-unroll literal
// (22-step unroll: 22 ≡ 0 mod 11, even). IT literal here (straight-line).
// Sentinels: VGPR ~125-145, WRITE_SIZE ~70 KB (R2: spill = 118 MB + 5x),
// FETCH ~75 MB (touches add no lines), absmax 0.
#define STEP(IT, PP)                                                          \
  {                                                                           \
    const int P   = (PP) % 11;                                                \
    const int cur = (PP) & 1;                                                 \
    const int nxt = ((PP) + 1) & 1;                                           \
    /* 1. demand prefetch row IT+1 into pb[nxt] (clamped; overshoot ok) */    \
    {                                                                         \
      int gy = y0 + (IT) + 1; if (gy > IMG_H - 1) gy = IMG_H - 1;             \
      const float* __restrict__ r1 = p1 + gy * IMG_W + colA;                  \
      const float* __restrict__ r2 = p2 + gy * IMG_W + colA;                  \
      _Pragma("unroll")                                                       \
      for (int k = 0; k < 6; ++k) {                                           \
        pb[nxt][0][k] = *(const v2f*)(r1 + 2 * k);                            \
        pb[nxt][1][k] = *(const v2f*)(r2 + 2 * k);                            \
      }                                                                       \
    }                                                                         \
    /* 1b. touch row IT+TD: fire-and-forget L2/L1 warming (IT literal) */     \
    if ((IT) + TD <= NROWS + 1) {                                             \
      int gty = y0 + (IT) + TD; if (gty > IMG_H - 1) gty = IMG_H - 1;         \
      tch[cur][0] = *(p1 + gty * IMG_W + tcol);                               \
      tch[cur][1] = *(p2 + gty * IMG_W + tcol);                               \
    }                                                                         \
    /* 2. h-pass on pb[cur] (row IT), packed over output cols (A,B) */        \
    v2f h1  = (v2f){0.f,0.f}, h2  = (v2f){0.f,0.f};                           \
    v2f h11 = (v2f){0.f,0.f}, h22 = (v2f){0.f,0.f}, h12 = (v2f){0.f,0.f};     \
    _Pragma("unroll")                                                         \
    for (int j = 0; j < 11; ++j) {                                            \
      const v2f wj = (v2f){WG[j], WG[j]};                                     \
      v2f q1, q2;                                                             \
      if (j & 1) {                                                            \
        q1 = (v2f){pb[cur][0][j >> 1].y, pb[cur][0][(j >> 1) + 1].x};         \
        q2 = (v2f){pb[cur][1][j >> 1].y, pb[cur][1][(j >> 1) + 1].x};         \
      } else {                                                                \
        q1 = pb[cur][0][j >> 1];                                              \
        q2 = pb[cur][1][j >> 1];                                              \
      }                                                                       \
      const v2f t1 = wj * q1;                                                 \
      const v2f t2 = wj * q2;                                                 \
      h1 += t1; h2 += t2;                                                     \
      h11 = pk_fma(t1, q1, h11);                                              \
      h22 = pk_fma(t2, q2, h22);                                              \
      h12 = pk_fma(t1, q2, h12);                                              \
    }                                                                         \
    /* 3. vertical ring update: 5 pk_fma per slot */                          \
    _Pragma("unroll")                                                         \
    for (int sl = 0; sl < 11; ++sl) {                                         \
      const float wt = WG[(P - sl + 11) % 11];                                \
      const v2f wv = (v2f){wt, wt};                                           \
      acc[sl][0] = pk_fma(wv, h1,  acc[sl][0]);                               \
      acc[sl][1] = pk_fma(wv, h2,  acc[sl][1]);                               \
      acc[sl][2] = pk_fma(wv, h11, acc[sl][2]);                               \
      acc[sl][3] = pk_fma(wv, h22, acc[sl][3]);                               \
      acc[sl][4] = pk_fma(wv, h12, acc[sl][4]);                               \
    }                                                                         \
    /* 4. slot sc got its w[10] tap -> output row y = IT-10 completes */      \
    const int sc = (P + 1) % 11;                                              \
    if ((IT) >= 10 && (y0 + (IT) - 10) < OUT_H) {                             \
      const v2f m1 = acc[sc][0], m2 = acc[sc][1];                             \
      const v2f msq1 = m1 * m1, msq2 = m2 * m2, mu12 = m1 * m2;               \
      const v2f two = (v2f){2.f, 2.f};                                        \
      const v2f c1v = (v2f){SSIM_C1, SSIM_C1};                                \
      const v2f c2v = (v2f){SSIM_C2, SSIM_C2};                                \
      const v2f vA = pk_fma(two, acc[sc][4] - mu12, c2v);                     \
      const v2f vB = (acc[sc][2] - msq1) + (acc[sc][3] - msq2) + c2v;         \
      const v2f num = pk_fma(two, mu12, c1v) * vA;                            \
      const v2f den = (msq1 + msq2 + c1v) * vB;                               \
      if (validA) lsum = fmaf(num.x, __builtin_amdgcn_rcpf(den.x), lsum);     \
      if (validB) lsum = fmaf(num.y, __builtin_amdgcn_rcpf(den.y), lsum);     \
    }                                                                         \
    _Pragma("unroll")                                                         \
    for (int ch = 0; ch < 5; ++ch) acc[sc][ch] = (v2f){0.f, 0.f};             \
  }

__global__ __launch_bounds__(64, 2) void ssim_main(
    const float* __restrict__ img1,
    const float* __restrict__ img2,
    float* __restrict__ partials)
{
    const int lane   = threadIdx.x;
    const int stripe = blockIdx.x;
    const int cy     = blockIdx.y;
    const int b      = blockIdx.z;
    const int x0 = SW * stripe;
    const int y0 = RCH * cy;

    const float* __restrict__ p1 = img1 + (size_t)b * (IMG_H * IMG_W);
    const float* __restrict__ p2 = img2 + (size_t)b * (IMG_H * IMG_W);

    // lane's 12-col demand window base (clamped; no-op for valid lanes)
    int colA = x0 + 2 * lane;
    if (colA > IMG_W - 12) colA = IMG_W - 12;   // 628, even -> 8B aligned

    // touch column: stride 3 < 32-dword line -> covers every 128B line of
    // [x0, x0+137]; clamped in-bounds.
    int tcol = x0 + 3 * lane;
    {
        int tmax = x0 + 137; if (tmax > IMG_W - 1) tmax = IMG_W - 1;
        if (tcol > tmax) tcol = tmax;
    }

    // lane l produces output cols x0+2l (A) and x0+2l+1 (B); lanes 0..62 valid
    const bool validA = (2 * lane     < SW) && (x0 + 2 * lane     < OUT_W);
    const bool validB = (2 * lane + 1 < SW) && (x0 + 2 * lane + 1 < OUT_W);

    // vertical ring: 5 channels (mu1, mu2, s11, s22, s12), each v2f over (A,B)
    v2f acc[11][5];
#pragma unroll
    for (int i = 0; i < 11; ++i)
#pragma unroll
        for (int ch = 0; ch < 5; ++ch) acc[i][ch] = (v2f){0.f, 0.f};

    float lsum = 0.f;

    // touch sinks: rotating pair (WAW distance 2 steps) + prologue sinks
    float tch[2][2];
    float ptch[TD - 1][2];

    // prologue touches: rows y0+1 .. y0+TD-1 (row y0 is demand-loaded next).
    // Issued FIRST -- longest latency pole; ramp steps 0..TD-2 get partial
    // lead, steady state from step ~TD-1 on has full ~TD-step lead.
#pragma unroll
    for (int r = 1; r < TD; ++r) {
        ptch[r - 1][0] = *(p1 + (y0 + r) * IMG_W + tcol);
        ptch[r - 1][1] = *(p2 + (y0 + r) * IMG_W + tcol);
    }

    // input-row ping-pong: pb[parity][image][pair 0..5]
    v2f pb[2][2][6];

    // prologue: demand row y0 -> pb[0]
    {
        const float* __restrict__ r1 = p1 + y0 * IMG_W + colA;
        const float* __restrict__ r2 = p2 + y0 * IMG_W + colA;
#pragma unroll
        for (int k = 0; k < 6; ++k) {
            pb[0][0][k] = *(const v2f*)(r1 + 2 * k);
            pb[0][1][k] = *(const v2f*)(r2 + 2 * k);
        }
    }

    // 34 rows: 22-step literal unroll + 12-step literal tail (proven shape)
#pragma unroll
    for (int p = 0; p < 22; ++p) STEP(p, p)
#pragma unroll
    for (int p = 0; p < 12; ++p) STEP(22 + p, p)

    // keep all touch results live (prevents DCE of the touch loads; single
    // waitcnt here at kernel end, harmless)
    asm volatile("" :: "v"(tch[0][0]), "v"(tch[0][1]),
                       "v"(tch[1][0]), "v"(tch[1][1]));
#pragma unroll
    for (int r = 0; r < TD - 1; ++r)
        asm volatile("" :: "v"(ptch[r][0]), "v"(ptch[r][1]));

    // wave-level reduction (64 lanes)
#pragma unroll
    for (int off = 32; off > 0; off >>= 1)
        lsum += __shfl_down(lsum, off);
    if (lane == 0)
        partials[(b * NCHUNK + cy) * NSTRIPE + stripe] = lsum;
}

__global__ __launch_bounds__(256) void ssim_reduce(
    const float* __restrict__ partials, float* __restrict__ out)
{
    const int n = NSTRIPE * NCHUNK * NBATCH;  // 3200
    __shared__ double red[256];
    int tid = threadIdx.x;
    double s = 0.0;
    for (int i = tid; i < n; i += 256) s += (double)partials[i];
    red[tid] = s;
    __syncthreads();
    for (int k = 128; k > 0; k >>= 1) {
        if (tid < k) red[tid] += red[tid + k];
        __syncthreads();
    }
    if (tid == 0) {
        double mean = red[0] / (double)((size_t)NBATCH * OUT_H * OUT_W);
        out[0] = (float)((1.0 - mean) * 0.5);
    }
}

extern "C" void kernel_launch(void* const* d_in, const int* in_sizes, int n_in,
                              void* d_out, int out_size, void* d_ws, size_t ws_size,
                              hipStream_t stream)
{
    const float* img1 = (const float*)d_in[0];
    const float* img2 = (const float*)d_in[1];
    float* out = (float*)d_out;
    float* partials = (float*)d_ws;  // 3200 floats = 12.8 KB

    dim3 grid(NSTRIPE, NCHUNK, NBATCH);  // 5 x 20 x 32 = 3200 single-wave blocks
    ssim_main<<<grid, dim3(64), 0, stream>>>(img1, img2, partials);
    ssim_reduce<<<1, dim3(256), 0, stream>>>(partials, out);
}